// Round 8
// baseline (265.315 us; speedup 1.0000x reference)
//
#include <hip/hip_runtime.h>
#include <hip/hip_bf16.h>
#include <stdint.h>

// Problem constants
#define S_LEN 2048
#define BATCH 2
#define EMB   1024
#define NH    16
#define DHEAD 64
#define ROWS  (S_LEN*BATCH)   // 4096
// DH^-0.5 * log2(e): scores produced in log2 domain so softmax uses raw v_exp_f32
#define SCALE_Q 0.18033688011112042f
#define DEFER_THR 11.0f       // log2-domain defer-max threshold (P <= 2^11)

typedef __attribute__((ext_vector_type(8))) short bf16x8;    // 8 bf16 in 4 VGPRs
typedef __attribute__((ext_vector_type(4))) float f32x4;
typedef __attribute__((ext_vector_type(16))) float f32x16;

typedef const __attribute__((address_space(1))) void* gas_ptr;
typedef __attribute__((address_space(3))) void* las_ptr;
// async global->LDS, 16B per lane, dest = wave-uniform base + lane*16
#define GLD16(g, l) __builtin_amdgcn_global_load_lds((gas_ptr)(g), (las_ptr)(l), 16, 0, 0)

__device__ __forceinline__ unsigned short f2b(float f) {
  union { float f; unsigned int u; } v; v.f = f;
  unsigned int u = v.u;
  unsigned int r = (u + 0x7FFFu + ((u >> 16) & 1u)) >> 16;  // RNE
  return (unsigned short)r;
}

__device__ __forceinline__ unsigned cvt_pk_bf16(float lo, float hi) {
  unsigned r;
  asm("v_cvt_pk_bf16_f32 %0, %1, %2" : "=v"(r) : "v"(lo), "v"(hi));
  return r;
}

// raw 2^x — single transcendental instruction, no ocml edge-case bloat
__device__ __forceinline__ float exp2_raw(float x) {
  float r;
  asm("v_exp_f32 %0, %1" : "=v"(r) : "v"(x));
  return r;
}

// ---------------- fused fp32 -> bf16 conversion (query + 4 weights) ----------------
__device__ __forceinline__ void cvt8(const float* __restrict__ s,
                                     unsigned short* __restrict__ d, size_t i) {
  float4 a = *reinterpret_cast<const float4*>(s + i);
  float4 b = *reinterpret_cast<const float4*>(s + i + 4);
  uint4 o;
  o.x = (unsigned)f2b(a.x) | ((unsigned)f2b(a.y) << 16);
  o.y = (unsigned)f2b(a.z) | ((unsigned)f2b(a.w) << 16);
  o.z = (unsigned)f2b(b.x) | ((unsigned)f2b(b.y) << 16);
  o.w = (unsigned)f2b(b.z) | ((unsigned)f2b(b.w) << 16);
  *reinterpret_cast<uint4*>(d + i) = o;
}

__global__ __launch_bounds__(256) void cvt_all_kernel(
    const float* __restrict__ query,
    const float* __restrict__ wq, const float* __restrict__ wk,
    const float* __restrict__ wv, const float* __restrict__ wo,
    unsigned short* __restrict__ Xbf,
    unsigned short* __restrict__ Wqb, unsigned short* __restrict__ Wkb,
    unsigned short* __restrict__ Wvb, unsigned short* __restrict__ Wob) {
  int id = blockIdx.x;
  const float* s; unsigned short* d; size_t off;
  if (id < 2048) { s = query; d = Xbf; off = (size_t)id * 2048; }
  else {
    int wsel = (id - 2048) >> 9;
    off = (size_t)((id - 2048) & 511) * 2048;
    switch (wsel) {
      case 0:  s = wq; d = Wqb; break;
      case 1:  s = wk; d = Wkb; break;
      case 2:  s = wv; d = Wvb; break;
      default: s = wo; d = Wob; break;
    }
  }
  cvt8(s, d, off + (size_t)threadIdx.x * 8);
}

// ---------------- GEMM mainloop (C = A * B^T), 128x128 tile, BK=64 ----------------
__device__ __forceinline__ void gemm_mainloop(const unsigned short* __restrict__ A,
                                              const unsigned short* __restrict__ Bw,
                                              int m0, int n0, f32x4 acc[4][4],
                                              unsigned short* Ab, unsigned short* Bb) {
  const int t    = threadIdx.x;
  const int lane = t & 63;
  const int w    = t >> 6;
  const int wr   = w >> 1, wc = w & 1;
  const int lm   = lane & 15;
  const int lq   = lane >> 4;

  f32x4 zf = {0.0f, 0.0f, 0.0f, 0.0f};
#pragma unroll
  for (int i = 0; i < 4; ++i)
#pragma unroll
    for (int j = 0; j < 4; ++j) acc[i][j] = zf;

  for (int k0 = 0; k0 < EMB; k0 += 64) {
#pragma unroll
    for (int q = 0; q < 4; ++q) {
      int c = t + q * 256;
      int r = c >> 3, ci = c & 7;
      int lc = ci ^ (r & 7);
      GLD16(A  + (size_t)(m0 + r) * EMB + k0 + lc * 8,
            (char*)Ab + (size_t)(q * 256 + w * 64) * 16);
      GLD16(Bw + (size_t)(n0 + r) * EMB + k0 + lc * 8,
            (char*)Bb + (size_t)(q * 256 + w * 64) * 16);
    }
    asm volatile("s_waitcnt vmcnt(0)" ::: "memory");
    __syncthreads();

#pragma unroll
    for (int kk = 0; kk < 2; ++kk) {
      bf16x8 af[4], bfr[4];
#pragma unroll
      for (int i = 0; i < 4; ++i) {
        int ra = wr * 64 + i * 16 + lm;
        af[i] = *reinterpret_cast<const bf16x8*>(
            &Ab[ra * 64 + ((kk * 4 + lq) ^ (ra & 7)) * 8]);
      }
#pragma unroll
      for (int j = 0; j < 4; ++j) {
        int rb = wc * 64 + j * 16 + lm;
        bfr[j] = *reinterpret_cast<const bf16x8*>(
            &Bb[rb * 64 + ((kk * 4 + lq) ^ (rb & 7)) * 8]);
      }
#pragma unroll
      for (int i = 0; i < 4; ++i)
#pragma unroll
        for (int j = 0; j < 4; ++j)
          acc[i][j] = __builtin_amdgcn_mfma_f32_16x16x32_bf16(af[i], bfr[j], acc[i][j], 0, 0, 0);
    }
    __syncthreads();
  }
}

// ---------------- QKV projection (V written pre-transposed + kv-permuted) ----------------
__global__ __launch_bounds__(256) void gemm_qkv_kernel(
    const unsigned short* __restrict__ X,
    const unsigned short* __restrict__ Wq, const unsigned short* __restrict__ Wk,
    const unsigned short* __restrict__ Wv,
    const float* __restrict__ bq, const float* __restrict__ bk, const float* __restrict__ bv,
    unsigned short* __restrict__ Qb, unsigned short* __restrict__ Kb,
    unsigned short* __restrict__ Vtg) {
  __shared__ unsigned short SH[2][128 * 64];
  const int m0 = blockIdx.x * 128;
  const int n0 = blockIdx.y * 128;
  const int z  = blockIdx.z;
  const unsigned short* Bw = (z == 0) ? Wq : (z == 1) ? Wk : Wv;
  const float* bias        = (z == 0) ? bq : (z == 1) ? bk : bv;

  f32x4 acc[4][4];
  gemm_mainloop(X, Bw, m0, n0, acc, SH[0], SH[1]);

  const int t    = threadIdx.x;
  const int lane = t & 63;
  const int w    = t >> 6;
  const int wr   = w >> 1, wc = w & 1;
  const int lm   = lane & 15, lq = lane >> 4;

  if (z != 2) {
    unsigned short* Out = (z == 0) ? Qb : Kb;
    const float scale   = (z == 0) ? SCALE_Q : 1.0f;
#pragma unroll
    for (int j = 0; j < 4; ++j) {
      int col = n0 + wc * 64 + j * 16 + lm;      // E index
      int h = col >> 6, dd = col & 63;
      float bc = bias[col];
#pragma unroll
      for (int i = 0; i < 4; ++i) {
#pragma unroll
        for (int r = 0; r < 4; ++r) {
          int row = m0 + wr * 64 + i * 16 + lq * 4 + r;   // s*B + b
          int s = row >> 1, b = row & 1;
          float v = (acc[i][j][r] + bc) * scale;
          Out[((size_t)(b * NH + h) * S_LEN + s) * DHEAD + dd] = f2b(v);
        }
      }
    }
  } else {
    // V: transpose in LDS, write Vt[bh][d][s'] with kv bits2<->3 swapped per
    // 16-group (matches attn's in-register P ordering for the PV MFMA).
    unsigned short* T = &SH[0][0];   // 128*128 shorts = 32 KB
#pragma unroll
    for (int j = 0; j < 4; ++j) {
      int col = wc * 64 + j * 16 + lm;           // local col 0..127
      float bc = bias[n0 + col];
#pragma unroll
      for (int i = 0; i < 4; ++i) {
#pragma unroll
        for (int r = 0; r < 4; ++r) {
          int row = wr * 64 + i * 16 + lq * 4 + r;   // local row 0..127
          int idx = (row & 1) * 64 + (row >> 1);
          int chunk = idx >> 3, within = idx & 7;
          int pchunk = (chunk & 8) | ((chunk ^ col) & 7);
          T[col * 128 + pchunk * 8 + within] = f2b(acc[i][j][r] + bc);
        }
      }
    }
    __syncthreads();
#pragma unroll
    for (int itr = 0; itr < 8; ++itr) {
      int u = (t >> 3) + itr * 32;
      int col = u & 127, b = u >> 7;
      int c3 = t & 7;
      int pchunk = (b * 8) | ((c3 ^ col) & 7);
      bf16x8 vv = *reinterpret_cast<const bf16x8*>(&T[col * 128 + pchunk * 8]);
      int h = (n0 + col) >> 6, dd = (n0 + col) & 63;
      unsigned short* dst =
          Vtg + ((size_t)(b * NH + h) * DHEAD + dd) * S_LEN + (m0 >> 1);
      // kv-permute store: 8-run c3*8 -> two 4-runs (swap bits 2,3)
      int p1 = ((c3 >> 1) << 4) | ((c3 & 1) << 2);
      union { bf16x8 v; uint4 u4; } cv; cv.v = vv;
      *reinterpret_cast<uint2*>(dst + p1)     = make_uint2(cv.u4.x, cv.u4.y);
      *reinterpret_cast<uint2*>(dst + p1 + 8) = make_uint2(cv.u4.z, cv.u4.w);
    }
  }
}

// ---------------- final projection: 64x128 tile (512 blocks = 2/CU) ----------------
__global__ __launch_bounds__(256) void gemm_out_kernel(
    const unsigned short* __restrict__ Ctx, const unsigned short* __restrict__ Wo,
    const float* __restrict__ bo, float* __restrict__ Out) {
  __shared__ unsigned short Ab[64 * 64];    // 8 KB
  __shared__ unsigned short Bb[128 * 64];   // 16 KB
  const int m0 = blockIdx.x * 64;
  const int n0 = blockIdx.y * 128;
  const int t    = threadIdx.x;
  const int lane = t & 63;
  const int w    = t >> 6;
  const int wr   = w >> 1, wc = w & 1;
  const int lm   = lane & 15, lq = lane >> 4;

  f32x4 zf = {0.0f, 0.0f, 0.0f, 0.0f};
  f32x4 acc[2][4];
#pragma unroll
  for (int i = 0; i < 2; ++i)
#pragma unroll
    for (int j = 0; j < 4; ++j) acc[i][j] = zf;

  for (int k0 = 0; k0 < EMB; k0 += 64) {
#pragma unroll
    for (int q = 0; q < 2; ++q) {
      int c = t + q * 256;
      int r = c >> 3, ci = c & 7;
      int lc = ci ^ (r & 7);
      GLD16(Ctx + (size_t)(m0 + r) * EMB + k0 + lc * 8,
            (char*)Ab + (size_t)(q * 256 + w * 64) * 16);
    }
#pragma unroll
    for (int q = 0; q < 4; ++q) {
      int c = t + q * 256;
      int r = c >> 3, ci = c & 7;
      int lc = ci ^ (r & 7);
      GLD16(Wo + (size_t)(n0 + r) * EMB + k0 + lc * 8,
            (char*)Bb + (size_t)(q * 256 + w * 64) * 16);
    }
    asm volatile("s_waitcnt vmcnt(0)" ::: "memory");
    __syncthreads();

#pragma unroll
    for (int kk = 0; kk < 2; ++kk) {
      bf16x8 af[2], bfr[4];
#pragma unroll
      for (int i = 0; i < 2; ++i) {
        int ra = wr * 32 + i * 16 + lm;
        af[i] = *reinterpret_cast<const bf16x8*>(
            &Ab[ra * 64 + ((kk * 4 + lq) ^ (ra & 7)) * 8]);
      }
#pragma unroll
      for (int j = 0; j < 4; ++j) {
        int rb = wc * 64 + j * 16 + lm;
        bfr[j] = *reinterpret_cast<const bf16x8*>(
            &Bb[rb * 64 + ((kk * 4 + lq) ^ (rb & 7)) * 8]);
      }
#pragma unroll
      for (int i = 0; i < 2; ++i)
#pragma unroll
        for (int j = 0; j < 4; ++j)
          acc[i][j] = __builtin_amdgcn_mfma_f32_16x16x32_bf16(af[i], bfr[j], acc[i][j], 0, 0, 0);
    }
    __syncthreads();
  }

#pragma unroll
  for (int j = 0; j < 4; ++j) {
    int col = n0 + wc * 64 + j * 16 + lm;
    float bc = bo[col];
#pragma unroll
    for (int i = 0; i < 2; ++i) {
#pragma unroll
      for (int r = 0; r < 4; ++r) {
        int row = m0 + wr * 32 + i * 16 + lq * 4 + r;
        Out[(size_t)row * EMB + col] = acc[i][j][r] + bc;
      }
    }
  }
}

// ---------------- flash attention: LDS-free, barrier-free, direct L2 reads ----------------
// 4 waves x 32 q, grid (32,16). No __shared__, no barriers: K/V tiles (8KB+8KB)
// are L1-resident and shared by the block's free-running waves; all 16 q-blocks
// of a bh sit on one XCD (bid=bh+32*qt, 32%8==0) so K/V stays L2-resident.
// K double-buffered in registers (prefetch tile t+1 before computing t);
// V loads issued at body top, consumed after softmax (~300cy cover).
__global__ __launch_bounds__(256) void attn_kernel(
    const unsigned short* __restrict__ Qb, const unsigned short* __restrict__ Kb,
    const unsigned short* __restrict__ Vtg, unsigned short* __restrict__ Ctx) {
  const int bh = blockIdx.x;
  const int q0 = blockIdx.y * 128;
  const int t    = threadIdx.x;
  const int lane = t & 63;
  const int w    = t >> 6;
  const int l31  = lane & 31;
  const int hh   = lane >> 5;
  const unsigned short* Q  = Qb  + (size_t)bh * S_LEN * DHEAD;
  const unsigned short* K  = Kb  + (size_t)bh * S_LEN * DHEAD;
  const unsigned short* Vt = Vtg + (size_t)bh * DHEAD * S_LEN;   // [d][s-permuted]

  const int qw = q0 + w * 32;

  // Q B-frags: lane holds col q = l31, k = kk*16 + hh*8 + e
  bf16x8 aq[4];
#pragma unroll
  for (int kk = 0; kk < 4; ++kk)
    aq[kk] = *reinterpret_cast<const bf16x8*>(
        Q + (size_t)(qw + l31) * DHEAD + kk * 16 + hh * 8);

  f32x16 z16 = {0.f,0.f,0.f,0.f, 0.f,0.f,0.f,0.f, 0.f,0.f,0.f,0.f, 0.f,0.f,0.f,0.f};
  f32x16 accO[2];               // O[q-rows][d = ni*32 + l31]
  accO[0] = z16; accO[1] = z16;
  float m_s = -1e30f, l_s = 0.0f;   // per lane, q = l31

  bf16x8 kfA[2][4], kfB[2][4], bv[2][2][2];

  // K A-frags for tile at kb: row kv = kb + ji*32 + l31, k-chunk kk*16+hh*8
#define LOADK(KF, kb)                                                        \
  {                                                                          \
    _Pragma("unroll")                                                        \
    for (int ji = 0; ji < 2; ++ji)                                           \
      _Pragma("unroll")                                                      \
      for (int kk = 0; kk < 4; ++kk)                                         \
        KF[ji][kk] = *reinterpret_cast<const bf16x8*>(                       \
            K + (size_t)((kb) + ji * 32 + l31) * DHEAD + kk * 16 + hh * 8);  \
  }
  // V B-frags (kv-permuted global layout): row d = ni*32+l31, 16B chunk
#define LOADV(kb)                                                            \
  {                                                                          \
    _Pragma("unroll")                                                        \
    for (int ni = 0; ni < 2; ++ni)                                           \
      _Pragma("unroll")                                                      \
      for (int ji = 0; ji < 2; ++ji)                                         \
        _Pragma("unroll")                                                    \
        for (int ss = 0; ss < 2; ++ss)                                       \
          bv[ni][ji][ss] = *reinterpret_cast<const bf16x8*>(                 \
              Vt + (size_t)(ni * 32 + l31) * S_LEN + (kb) +                  \
              (ji * 4 + ss * 2 + hh) * 8);                                   \
  }

#define COMPUTE(KF)                                                          \
  {                                                                          \
    f32x16 p32[2];                                                           \
    __builtin_amdgcn_s_setprio(1);                                           \
    _Pragma("unroll")                                                        \
    for (int ji = 0; ji < 2; ++ji) {                                         \
      f32x16 a = z16;                                                        \
      _Pragma("unroll")                                                      \
      for (int kk = 0; kk < 4; ++kk)                                         \
        a = __builtin_amdgcn_mfma_f32_32x32x16_bf16(KF[ji][kk], aq[kk], a, 0, 0, 0); \
      p32[ji] = a;                                                           \
    }                                                                        \
    __builtin_amdgcn_s_setprio(0);                                           \
    float t8[8];                                                             \
    _Pragma("unroll")                                                        \
    for (int e = 0; e < 8; ++e)                                              \
      t8[e] = fmaxf(fmaxf(p32[0][e], p32[0][e + 8]),                         \
                    fmaxf(p32[1][e], p32[1][e + 8]));                        \
    float u0 = fmaxf(t8[0], t8[4]), u1 = fmaxf(t8[1], t8[5]);                \
    float u2 = fmaxf(t8[2], t8[6]), u3 = fmaxf(t8[3], t8[7]);                \
    float tm = fmaxf(fmaxf(u0, u1), fmaxf(u2, u3));                          \
    tm = fmaxf(tm, __shfl_xor(tm, 32));                                      \
    if (!__all(tm - m_s <= DEFER_THR)) {                                     \
      float mn = fmaxf(m_s, tm);                                             \
      float sc = exp2_raw(m_s - mn);                                         \
      l_s *= sc;                                                             \
      m_s = mn;                                                              \
      _Pragma("unroll")                                                      \
      for (int r = 0; r < 16; ++r) {                                         \
        float scr = __shfl(sc, (r & 3) + 8 * (r >> 2) + 4 * hh);             \
        accO[0][r] *= scr;                                                   \
        accO[1][r] *= scr;                                                   \
      }                                                                      \
    }                                                                        \
    _Pragma("unroll")                                                        \
    for (int e = 0; e < 16; ++e) {                                           \
      p32[0][e] = exp2_raw(p32[0][e] - m_s);                                 \
      p32[1][e] = exp2_raw(p32[1][e] - m_s);                                 \
    }                                                                        \
    float s8[8];                                                             \
    _Pragma("unroll")                                                        \
    for (int e = 0; e < 8; ++e)                                              \
      s8[e] = (p32[0][e] + p32[0][e + 8]) + (p32[1][e] + p32[1][e + 8]);     \
    float v0 = (s8[0] + s8[4]) + (s8[1] + s8[5]);                            \
    float v1 = (s8[2] + s8[6]) + (s8[3] + s8[7]);                            \
    float ps = v0 + v1;                                                      \
    ps += __shfl_xor(ps, 32);                                                \
    l_s += ps;                                                               \
    bf16x8 pa[2][2];                                                         \
    _Pragma("unroll")                                                        \
    for (int ji = 0; ji < 2; ++ji) {                                         \
      uint4 lo4, hi4;                                                        \
      lo4.x = cvt_pk_bf16(p32[ji][0],  p32[ji][1]);                          \
      lo4.y = cvt_pk_bf16(p32[ji][2],  p32[ji][3]);                          \
      lo4.z = cvt_pk_bf16(p32[ji][4],  p32[ji][5]);                          \
      lo4.w = cvt_pk_bf16(p32[ji][6],  p32[ji][7]);                          \
      hi4.x = cvt_pk_bf16(p32[ji][8],  p32[ji][9]);                          \
      hi4.y = cvt_pk_bf16(p32[ji][10], p32[ji][11]);                         \
      hi4.z = cvt_pk_bf16(p32[ji][12], p32[ji][13]);                         \
      hi4.w = cvt_pk_bf16(p32[ji][14], p32[ji][15]);                         \
      pa[ji][0] = *reinterpret_cast<bf16x8*>(&lo4);                          \
      pa[ji][1] = *reinterpret_cast<bf16x8*>(&hi4);                          \
    }                                                                        \
    __builtin_amdgcn_s_setprio(1);                                           \
    _Pragma("unroll")                                                        \
    for (int ni = 0; ni < 2; ++ni)                                           \
      _Pragma("unroll")                                                      \
      for (int ji = 0; ji < 2; ++ji)                                         \
        _Pragma("unroll")                                                    \
        for (int ss = 0; ss < 2; ++ss)                                       \
          accO[ni] = __builtin_amdgcn_mfma_f32_32x32x16_bf16(                \
              pa[ji][ss], bv[ni][ji][ss], accO[ni], 0, 0, 0);                \
    __builtin_amdgcn_s_setprio(0);                                           \
  }

  const int NT = S_LEN / 64;
  LOADK(kfA, 0);
  for (int it = 0; it < NT; it += 2) {
    LOADK(kfB, (it + 1) * 64);          // prefetch K for tile it+1
    LOADV(it * 64);                     // V for tile it (consumed after softmax)
    COMPUTE(kfA);
    if (it + 2 < NT) LOADK(kfA, (it + 2) * 64);
    LOADV((it + 1) * 64);
    COMPUTE(kfB);
  }

  // ---- epilogue: normalize, write ctx [S,B,E] bf16 ----
  const int b = bh >> 4, h = bh & 15;
#pragma unroll
  for (int r = 0; r < 16; ++r) {
    int row = (r & 3) + 8 * (r >> 2) + 4 * hh;
    float rl = 1.0f / __shfl(l_s, row);
    int srow = qw + row;
    size_t base = ((size_t)srow * BATCH + b) * EMB + (size_t)h * 64 + l31;
    Ctx[base]      = f2b(accO[0][r] * rl);
    Ctx[base + 32] = f2b(accO[1][r] * rl);
  }
}

// ---------------- launch ----------------
extern "C" void kernel_launch(void* const* d_in, const int* in_sizes, int n_in,
                              void* d_out, int out_size, void* d_ws, size_t ws_size,
                              hipStream_t stream) {
  const float* query = (const float*)d_in[0];
  const float* wq = (const float*)d_in[1];
  const float* bq = (const float*)d_in[2];
  const float* wk = (const float*)d_in[3];
  const float* bk = (const float*)d_in[4];
  const float* wv = (const float*)d_in[5];
  const float* bv = (const float*)d_in[6];
  const float* wo = (const float*)d_in[7];
  const float* bo = (const float*)d_in[8];
  float* out = (float*)d_out;

  unsigned short* p = (unsigned short*)d_ws;
  unsigned short* Xbf = p;                        p += (size_t)ROWS * EMB;
  unsigned short* Wqb = p;                        p += (size_t)EMB * EMB;
  unsigned short* Wkb = p;                        p += (size_t)EMB * EMB;
  unsigned short* Wvb = p;                        p += (size_t)EMB * EMB;
  unsigned short* Wob = p;                        p += (size_t)EMB * EMB;
  unsigned short* Qb  = p;                        p += (size_t)ROWS * EMB;   // [B,H,S,DH]
  unsigned short* Kb  = p;                        p += (size_t)ROWS * EMB;   // [B,H,S,DH]
  unsigned short* Vtg = p;                        p += (size_t)ROWS * EMB;   // [B,H,DH,S] kv-permuted
  unsigned short* Ctx = p;                        p += (size_t)ROWS * EMB;

  cvt_all_kernel<<<4096, 256, 0, stream>>>(query, wq, wk, wv, wo,
                                           Xbf, Wqb, Wkb, Wvb, Wob);
  gemm_qkv_kernel<<<dim3(ROWS / 128, EMB / 128, 3), 256, 0, stream>>>(
      Xbf, Wqb, Wkb, Wvb, bq, bk, bv, Qb, Kb, Vtg);
  attn_kernel<<<dim3(BATCH * NH, S_LEN / 128), 256, 0, stream>>>(Qb, Kb, Vtg, Ctx);
  gemm_out_kernel<<<dim3(ROWS / 64, EMB / 128), 256, 0, stream>>>(Ctx, Wob, bo, out);
}

// Round 9
// 194.945 us; speedup vs baseline: 1.3610x; 1.3610x over previous
//
#include <hip/hip_runtime.h>
#include <hip/hip_bf16.h>
#include <stdint.h>

// Problem constants
#define S_LEN 2048
#define BATCH 2
#define EMB   1024
#define NH    16
#define DHEAD 64
#define ROWS  (S_LEN*BATCH)   // 4096
// DH^-0.5 * log2(e): scores produced in log2 domain so softmax uses raw v_exp_f32
#define SCALE_Q 0.18033688011112042f
#define DEFER_THR 11.0f       // log2-domain defer-max threshold (P <= 2^11)

typedef __attribute__((ext_vector_type(8))) short bf16x8;    // 8 bf16 in 4 VGPRs
typedef __attribute__((ext_vector_type(4))) float f32x4;
typedef __attribute__((ext_vector_type(16))) float f32x16;

typedef const __attribute__((address_space(1))) void* gas_ptr;
typedef __attribute__((address_space(3))) void* las_ptr;
// async global->LDS, 16B per lane, dest = wave-uniform base + lane*16
#define GLD16(g, l) __builtin_amdgcn_global_load_lds((gas_ptr)(g), (las_ptr)(l), 16, 0, 0)

__device__ __forceinline__ unsigned short f2b(float f) {
  union { float f; unsigned int u; } v; v.f = f;
  unsigned int u = v.u;
  unsigned int r = (u + 0x7FFFu + ((u >> 16) & 1u)) >> 16;  // RNE
  return (unsigned short)r;
}

__device__ __forceinline__ unsigned cvt_pk_bf16(float lo, float hi) {
  unsigned r;
  asm("v_cvt_pk_bf16_f32 %0, %1, %2" : "=v"(r) : "v"(lo), "v"(hi));
  return r;
}

// raw 2^x — single transcendental instruction, no ocml edge-case bloat
__device__ __forceinline__ float exp2_raw(float x) {
  float r;
  asm("v_exp_f32 %0, %1" : "=v"(r) : "v"(x));
  return r;
}

// ---------------- fused fp32 -> bf16 conversion (query + 4 weights) ----------------
__device__ __forceinline__ void cvt8(const float* __restrict__ s,
                                     unsigned short* __restrict__ d, size_t i) {
  float4 a = *reinterpret_cast<const float4*>(s + i);
  float4 b = *reinterpret_cast<const float4*>(s + i + 4);
  uint4 o;
  o.x = (unsigned)f2b(a.x) | ((unsigned)f2b(a.y) << 16);
  o.y = (unsigned)f2b(a.z) | ((unsigned)f2b(a.w) << 16);
  o.z = (unsigned)f2b(b.x) | ((unsigned)f2b(b.y) << 16);
  o.w = (unsigned)f2b(b.z) | ((unsigned)f2b(b.w) << 16);
  *reinterpret_cast<uint4*>(d + i) = o;
}

__global__ __launch_bounds__(256) void cvt_all_kernel(
    const float* __restrict__ query,
    const float* __restrict__ wq, const float* __restrict__ wk,
    const float* __restrict__ wv, const float* __restrict__ wo,
    unsigned short* __restrict__ Xbf,
    unsigned short* __restrict__ Wqb, unsigned short* __restrict__ Wkb,
    unsigned short* __restrict__ Wvb, unsigned short* __restrict__ Wob) {
  int id = blockIdx.x;
  const float* s; unsigned short* d; size_t off;
  if (id < 2048) { s = query; d = Xbf; off = (size_t)id * 2048; }
  else {
    int wsel = (id - 2048) >> 9;
    off = (size_t)((id - 2048) & 511) * 2048;
    switch (wsel) {
      case 0:  s = wq; d = Wqb; break;
      case 1:  s = wk; d = Wkb; break;
      case 2:  s = wv; d = Wvb; break;
      default: s = wo; d = Wob; break;
    }
  }
  cvt8(s, d, off + (size_t)threadIdx.x * 8);
}

// ---------------- GEMM mainloop (C = A * B^T), 128x128 tile, BK=64 ----------------
__device__ __forceinline__ void gemm_mainloop(const unsigned short* __restrict__ A,
                                              const unsigned short* __restrict__ Bw,
                                              int m0, int n0, f32x4 acc[4][4],
                                              unsigned short* Ab, unsigned short* Bb) {
  const int t    = threadIdx.x;
  const int lane = t & 63;
  const int w    = t >> 6;
  const int wr   = w >> 1, wc = w & 1;
  const int lm   = lane & 15;
  const int lq   = lane >> 4;

  f32x4 zf = {0.0f, 0.0f, 0.0f, 0.0f};
#pragma unroll
  for (int i = 0; i < 4; ++i)
#pragma unroll
    for (int j = 0; j < 4; ++j) acc[i][j] = zf;

  for (int k0 = 0; k0 < EMB; k0 += 64) {
#pragma unroll
    for (int q = 0; q < 4; ++q) {
      int c = t + q * 256;
      int r = c >> 3, ci = c & 7;
      int lc = ci ^ (r & 7);
      GLD16(A  + (size_t)(m0 + r) * EMB + k0 + lc * 8,
            (char*)Ab + (size_t)(q * 256 + w * 64) * 16);
      GLD16(Bw + (size_t)(n0 + r) * EMB + k0 + lc * 8,
            (char*)Bb + (size_t)(q * 256 + w * 64) * 16);
    }
    asm volatile("s_waitcnt vmcnt(0)" ::: "memory");
    __syncthreads();

#pragma unroll
    for (int kk = 0; kk < 2; ++kk) {
      bf16x8 af[4], bfr[4];
#pragma unroll
      for (int i = 0; i < 4; ++i) {
        int ra = wr * 64 + i * 16 + lm;
        af[i] = *reinterpret_cast<const bf16x8*>(
            &Ab[ra * 64 + ((kk * 4 + lq) ^ (ra & 7)) * 8]);
      }
#pragma unroll
      for (int j = 0; j < 4; ++j) {
        int rb = wc * 64 + j * 16 + lm;
        bfr[j] = *reinterpret_cast<const bf16x8*>(
            &Bb[rb * 64 + ((kk * 4 + lq) ^ (rb & 7)) * 8]);
      }
#pragma unroll
      for (int i = 0; i < 4; ++i)
#pragma unroll
        for (int j = 0; j < 4; ++j)
          acc[i][j] = __builtin_amdgcn_mfma_f32_16x16x32_bf16(af[i], bfr[j], acc[i][j], 0, 0, 0);
    }
    __syncthreads();
  }
}

// ---------------- QKV projection (V written pre-transposed + kv-permuted) ----------------
__global__ __launch_bounds__(256) void gemm_qkv_kernel(
    const unsigned short* __restrict__ X,
    const unsigned short* __restrict__ Wq, const unsigned short* __restrict__ Wk,
    const unsigned short* __restrict__ Wv,
    const float* __restrict__ bq, const float* __restrict__ bk, const float* __restrict__ bv,
    unsigned short* __restrict__ Qb, unsigned short* __restrict__ Kb,
    unsigned short* __restrict__ Vtg) {
  __shared__ unsigned short SH[2][128 * 64];
  const int m0 = blockIdx.x * 128;
  const int n0 = blockIdx.y * 128;
  const int z  = blockIdx.z;
  const unsigned short* Bw = (z == 0) ? Wq : (z == 1) ? Wk : Wv;
  const float* bias        = (z == 0) ? bq : (z == 1) ? bk : bv;

  f32x4 acc[4][4];
  gemm_mainloop(X, Bw, m0, n0, acc, SH[0], SH[1]);

  const int t    = threadIdx.x;
  const int lane = t & 63;
  const int w    = t >> 6;
  const int wr   = w >> 1, wc = w & 1;
  const int lm   = lane & 15, lq = lane >> 4;

  if (z != 2) {
    unsigned short* Out = (z == 0) ? Qb : Kb;
    const float scale   = (z == 0) ? SCALE_Q : 1.0f;
#pragma unroll
    for (int j = 0; j < 4; ++j) {
      int col = n0 + wc * 64 + j * 16 + lm;      // E index
      int h = col >> 6, dd = col & 63;
      float bc = bias[col];
#pragma unroll
      for (int i = 0; i < 4; ++i) {
#pragma unroll
        for (int r = 0; r < 4; ++r) {
          int row = m0 + wr * 64 + i * 16 + lq * 4 + r;   // s*B + b
          int s = row >> 1, b = row & 1;
          float v = (acc[i][j][r] + bc) * scale;
          Out[((size_t)(b * NH + h) * S_LEN + s) * DHEAD + dd] = f2b(v);
        }
      }
    }
  } else {
    // V: transpose in LDS, write Vt[bh][d][s'] with kv bits2<->3 swapped per
    // 16-group (matches attn's in-register P ordering for the PV MFMA).
    unsigned short* T = &SH[0][0];   // 128*128 shorts = 32 KB
#pragma unroll
    for (int j = 0; j < 4; ++j) {
      int col = wc * 64 + j * 16 + lm;           // local col 0..127
      float bc = bias[n0 + col];
#pragma unroll
      for (int i = 0; i < 4; ++i) {
#pragma unroll
        for (int r = 0; r < 4; ++r) {
          int row = wr * 64 + i * 16 + lq * 4 + r;   // local row 0..127
          int idx = (row & 1) * 64 + (row >> 1);
          int chunk = idx >> 3, within = idx & 7;
          int pchunk = (chunk & 8) | ((chunk ^ col) & 7);
          T[col * 128 + pchunk * 8 + within] = f2b(acc[i][j][r] + bc);
        }
      }
    }
    __syncthreads();
#pragma unroll
    for (int itr = 0; itr < 8; ++itr) {
      int u = (t >> 3) + itr * 32;
      int col = u & 127, b = u >> 7;
      int c3 = t & 7;
      int pchunk = (b * 8) | ((c3 ^ col) & 7);
      bf16x8 vv = *reinterpret_cast<const bf16x8*>(&T[col * 128 + pchunk * 8]);
      int h = (n0 + col) >> 6, dd = (n0 + col) & 63;
      unsigned short* dst =
          Vtg + ((size_t)(b * NH + h) * DHEAD + dd) * S_LEN + (m0 >> 1);
      // kv-permute store: 8-run c3*8 -> two 4-runs (swap bits 2,3)
      int p1 = ((c3 >> 1) << 4) | ((c3 & 1) << 2);
      union { bf16x8 v; uint4 u4; } cv; cv.v = vv;
      *reinterpret_cast<uint2*>(dst + p1)     = make_uint2(cv.u4.x, cv.u4.y);
      *reinterpret_cast<uint2*>(dst + p1 + 8) = make_uint2(cv.u4.z, cv.u4.w);
    }
  }
}

// ---------------- final projection: 64x128 tile (512 blocks = 2/CU) ----------------
__global__ __launch_bounds__(256) void gemm_out_kernel(
    const unsigned short* __restrict__ Ctx, const unsigned short* __restrict__ Wo,
    const float* __restrict__ bo, float* __restrict__ Out) {
  __shared__ unsigned short Ab[64 * 64];    // 8 KB
  __shared__ unsigned short Bb[128 * 64];   // 16 KB
  const int m0 = blockIdx.x * 64;
  const int n0 = blockIdx.y * 128;
  const int t    = threadIdx.x;
  const int lane = t & 63;
  const int w    = t >> 6;
  const int wr   = w >> 1, wc = w & 1;
  const int lm   = lane & 15, lq = lane >> 4;

  f32x4 zf = {0.0f, 0.0f, 0.0f, 0.0f};
  f32x4 acc[2][4];
#pragma unroll
  for (int i = 0; i < 2; ++i)
#pragma unroll
    for (int j = 0; j < 4; ++j) acc[i][j] = zf;

  for (int k0 = 0; k0 < EMB; k0 += 64) {
#pragma unroll
    for (int q = 0; q < 2; ++q) {
      int c = t + q * 256;
      int r = c >> 3, ci = c & 7;
      int lc = ci ^ (r & 7);
      GLD16(Ctx + (size_t)(m0 + r) * EMB + k0 + lc * 8,
            (char*)Ab + (size_t)(q * 256 + w * 64) * 16);
    }
#pragma unroll
    for (int q = 0; q < 4; ++q) {
      int c = t + q * 256;
      int r = c >> 3, ci = c & 7;
      int lc = ci ^ (r & 7);
      GLD16(Wo + (size_t)(n0 + r) * EMB + k0 + lc * 8,
            (char*)Bb + (size_t)(q * 256 + w * 64) * 16);
    }
    asm volatile("s_waitcnt vmcnt(0)" ::: "memory");
    __syncthreads();

#pragma unroll
    for (int kk = 0; kk < 2; ++kk) {
      bf16x8 af[2], bfr[4];
#pragma unroll
      for (int i = 0; i < 2; ++i) {
        int ra = wr * 32 + i * 16 + lm;
        af[i] = *reinterpret_cast<const bf16x8*>(
            &Ab[ra * 64 + ((kk * 4 + lq) ^ (ra & 7)) * 8]);
      }
#pragma unroll
      for (int j = 0; j < 4; ++j) {
        int rb = wc * 64 + j * 16 + lm;
        bfr[j] = *reinterpret_cast<const bf16x8*>(
            &Bb[rb * 64 + ((kk * 4 + lq) ^ (rb & 7)) * 8]);
      }
#pragma unroll
      for (int i = 0; i < 2; ++i)
#pragma unroll
        for (int j = 0; j < 4; ++j)
          acc[i][j] = __builtin_amdgcn_mfma_f32_16x16x32_bf16(af[i], bfr[j], acc[i][j], 0, 0, 0);
    }
    __syncthreads();
  }

#pragma unroll
  for (int j = 0; j < 4; ++j) {
    int col = n0 + wc * 64 + j * 16 + lm;
    float bc = bo[col];
#pragma unroll
    for (int i = 0; i < 2; ++i) {
#pragma unroll
      for (int r = 0; r < 4; ++r) {
        int row = m0 + wr * 32 + i * 16 + lq * 4 + r;
        Out[(size_t)row * EMB + col] = acc[i][j][r] + bc;
      }
    }
  }
}

// ---------------- flash attention: 32x32x16 MFMA, kv-split across wave halves ----------------
// 8 waves x 32 q = 128 q/block over 2 kv-halves: waves 0-3 do kv [0,1024),
// waves 4-7 do kv [1024,2048) -- doubles waves/SIMD (4) vs R7 at identical
// HBM traffic. Each half double-buffers K/V in its own 32KB LDS region;
// counted-vmcnt 2-deep pipeline, raw s_barrier. Final flash-decode merge of
// the two online-softmax states through LDS (staging region reused).
__global__ __launch_bounds__(512, 4) void attn_kernel(
    const unsigned short* __restrict__ Qb, const unsigned short* __restrict__ Kb,
    const unsigned short* __restrict__ Vtg, unsigned short* __restrict__ Ctx) {
  const int bh = blockIdx.x;
  const int q0 = blockIdx.y * 128;
  const int t    = threadIdx.x;
  const int lane = t & 63;
  const int w    = t >> 6;        // 0..7
  const int hf   = w >> 2;        // kv half
  const int wl   = w & 3;         // wave within half
  const int th   = t & 255;       // thread within half
  const int l31  = lane & 31;
  const int hh   = lane >> 5;
  const unsigned short* Q  = Qb  + (size_t)bh * S_LEN * DHEAD;
  const unsigned short* K  = Kb  + (size_t)bh * S_LEN * DHEAD;
  const unsigned short* Vt = Vtg + (size_t)bh * DHEAD * S_LEN;   // [d][s-permuted]

  alignas(16) __shared__ char SMEM[65536];
  unsigned short* Kl = (unsigned short*)(SMEM + hf * 32768);           // [2][4096]
  unsigned short* Vl = (unsigned short*)(SMEM + hf * 32768 + 16384);   // [2][4096]

  const int qw = q0 + wl * 32;

  // Q B-frags: lane holds col q = l31, k = kk*16 + hh*8 + e
  bf16x8 aq[4];
#pragma unroll
  for (int kk = 0; kk < 4; ++kk)
    aq[kk] = *reinterpret_cast<const bf16x8*>(
        Q + (size_t)(qw + l31) * DHEAD + kk * 16 + hh * 8);

  f32x16 z16 = {0.f,0.f,0.f,0.f, 0.f,0.f,0.f,0.f, 0.f,0.f,0.f,0.f, 0.f,0.f,0.f,0.f};
  f32x16 accO[2];               // C-frag: row = q, col d = ni*32 + l31
  accO[0] = z16; accO[1] = z16;
  float m_s = -1e30f, l_s = 0.0f;   // per lane, q = l31

  auto STAGE = [&](int b, int kb) {   // kb = global kv base of the 64-tile
#pragma unroll
    for (int q = 0; q < 2; ++q) {
      int c = th + q * 256;
      int r = c >> 3, pp = c & 7;
      int lc = pp ^ (r & 7);
      GLD16(K + (size_t)(kb + r) * DHEAD + lc * 8,
            (char*)Kl + (size_t)b * 8192 + (size_t)(q * 256 + wl * 64) * 16);
      GLD16(Vt + (size_t)r * S_LEN + kb + lc * 8,
            (char*)Vl + (size_t)b * 8192 + (size_t)(q * 256 + wl * 64) * 16);
    }
  };

  const int kvbase = hf * (S_LEN / 2);
  const int NT = S_LEN / 2 / 64;    // 16 tiles per half
  STAGE(0, kvbase);
  STAGE(1, kvbase + 64);

  for (int it = 0; it < NT; ++it) {
    const int cur = it & 1;
    if (it < NT - 1) {
      asm volatile("s_waitcnt vmcnt(4)" ::: "memory");
    } else {
      asm volatile("s_waitcnt vmcnt(0)" ::: "memory");
    }
    __builtin_amdgcn_s_barrier();   // tile-it loads landed for all waves

    const unsigned short* Klc = Kl + cur * 4096;
    const unsigned short* Vlc = Vl + cur * 4096;

    // ---- S^T = K Q^T (log2 domain): p32[ji] C-frag, col q = l31 ----
    f32x16 p32[2];
    __builtin_amdgcn_s_setprio(1);
#pragma unroll
    for (int ji = 0; ji < 2; ++ji) {
      f32x16 a = z16;
      int rr = ji * 32 + l31;
#pragma unroll
      for (int kk = 0; kk < 4; ++kk) {
        bf16x8 kf = *reinterpret_cast<const bf16x8*>(
            &Klc[rr * 64 + ((kk * 2 + hh) ^ (rr & 7)) * 8]);
        a = __builtin_amdgcn_mfma_f32_32x32x16_bf16(kf, aq[kk], a, 0, 0, 0);
      }
      p32[ji] = a;
    }
    __builtin_amdgcn_s_setprio(0);

    // ---- online softmax (per lane, q = l31) ----
    float t8[8];
#pragma unroll
    for (int e = 0; e < 8; ++e)
      t8[e] = fmaxf(fmaxf(p32[0][e], p32[0][e + 8]),
                    fmaxf(p32[1][e], p32[1][e + 8]));
    float u0 = fmaxf(t8[0], t8[4]), u1 = fmaxf(t8[1], t8[5]);
    float u2 = fmaxf(t8[2], t8[6]), u3 = fmaxf(t8[3], t8[7]);
    float tm = fmaxf(fmaxf(u0, u1), fmaxf(u2, u3));
    tm = fmaxf(tm, __shfl_xor(tm, 32));

    if (!__all(tm - m_s <= DEFER_THR)) {
      float mn = fmaxf(m_s, tm);
      float sc = exp2_raw(m_s - mn);
      l_s *= sc;
      m_s = mn;
#pragma unroll
      for (int r = 0; r < 16; ++r) {
        float scr = __shfl(sc, (r & 3) + 8 * (r >> 2) + 4 * hh);
        accO[0][r] *= scr;
        accO[1][r] *= scr;
      }
    }

#pragma unroll
    for (int e = 0; e < 16; ++e) {
      p32[0][e] = exp2_raw(p32[0][e] - m_s);
      p32[1][e] = exp2_raw(p32[1][e] - m_s);
    }
    float s8[8];
#pragma unroll
    for (int e = 0; e < 8; ++e)
      s8[e] = (p32[0][e] + p32[0][e + 8]) + (p32[1][e] + p32[1][e + 8]);
    float v0 = (s8[0] + s8[4]) + (s8[1] + s8[5]);
    float v1 = (s8[2] + s8[6]) + (s8[3] + s8[7]);
    float ps = v0 + v1;
    ps += __shfl_xor(ps, 32);
    l_s += ps;

    // ---- P -> bf16 A-frags in-register (kv-order matches V layout) ----
    bf16x8 pa[2][2];
#pragma unroll
    for (int ji = 0; ji < 2; ++ji) {
      uint4 lo4, hi4;
      lo4.x = cvt_pk_bf16(p32[ji][0],  p32[ji][1]);
      lo4.y = cvt_pk_bf16(p32[ji][2],  p32[ji][3]);
      lo4.z = cvt_pk_bf16(p32[ji][4],  p32[ji][5]);
      lo4.w = cvt_pk_bf16(p32[ji][6],  p32[ji][7]);
      hi4.x = cvt_pk_bf16(p32[ji][8],  p32[ji][9]);
      hi4.y = cvt_pk_bf16(p32[ji][10], p32[ji][11]);
      hi4.z = cvt_pk_bf16(p32[ji][12], p32[ji][13]);
      hi4.w = cvt_pk_bf16(p32[ji][14], p32[ji][15]);
      pa[ji][0] = *reinterpret_cast<bf16x8*>(&lo4);
      pa[ji][1] = *reinterpret_cast<bf16x8*>(&hi4);
    }

    // ---- O += P V ----
    __builtin_amdgcn_s_setprio(1);
#pragma unroll
    for (int ni = 0; ni < 2; ++ni) {
      int dd = ni * 32 + l31;
#pragma unroll
      for (int ji = 0; ji < 2; ++ji)
#pragma unroll
        for (int ss = 0; ss < 2; ++ss) {
          bf16x8 bv = *reinterpret_cast<const bf16x8*>(
              &Vlc[dd * 64 + ((ji * 4 + ss * 2 + hh) ^ (dd & 7)) * 8]);
          accO[ni] = __builtin_amdgcn_mfma_f32_32x32x16_bf16(pa[ji][ss], bv, accO[ni], 0, 0, 0);
        }
    }
    __builtin_amdgcn_s_setprio(0);

    // all LDS reads of buf[cur] retired before reuse barrier
    asm volatile("s_waitcnt lgkmcnt(0)" ::: "memory");
    __builtin_amdgcn_sched_barrier(0);
    __builtin_amdgcn_s_barrier();

    if (it + 2 < NT) STAGE(cur, kvbase + (it + 2) * 64);
  }

  // ---- flash-decode merge of the two kv-halves (LDS reused after final barrier)
  float* MB = (float*)SMEM;
  const int MS = 35;                      // stride 35 floats: conflict-light
  const int mb = (wl * 64 + lane) * MS;
  if (hf == 1) {
    MB[mb]     = m_s;
    MB[mb + 1] = l_s;
#pragma unroll
    for (int r = 0; r < 16; ++r) {
      MB[mb + 2 + r]  = accO[0][r];
      MB[mb + 18 + r] = accO[1][r];
    }
  }
  __syncthreads();
  if (hf == 0) {
    float m1 = MB[mb], l1 = MB[mb + 1];
    float mn  = fmaxf(m_s, m1);
    float sc0 = exp2_raw(m_s - mn);
    float sc1 = exp2_raw(m1 - mn);
    float lf  = l_s * sc0 + l1 * sc1;
    const int b = bh >> 4, h = bh & 15;
#pragma unroll
    for (int r = 0; r < 16; ++r) {
      int row = (r & 3) + 8 * (r >> 2) + 4 * hh;
      float s0 = __shfl(sc0, row);
      float s1 = __shfl(sc1, row);
      float rl = 1.0f / __shfl(lf, row);
      float o0 = (accO[0][r] * s0 + MB[mb + 2 + r]  * s1) * rl;
      float o1 = (accO[1][r] * s0 + MB[mb + 18 + r] * s1) * rl;
      int srow = qw + row;
      size_t base = ((size_t)srow * BATCH + b) * EMB + (size_t)h * 64 + l31;
      Ctx[base]      = f2b(o0);
      Ctx[base + 32] = f2b(o1);
    }
  }
}

// ---------------- launch ----------------
extern "C" void kernel_launch(void* const* d_in, const int* in_sizes, int n_in,
                              void* d_out, int out_size, void* d_ws, size_t ws_size,
                              hipStream_t stream) {
  const float* query = (const float*)d_in[0];
  const float* wq = (const float*)d_in[1];
  const float* bq = (const float*)d_in[2];
  const float* wk = (const float*)d_in[3];
  const float* bk = (const float*)d_in[4];
  const float* wv = (const float*)d_in[5];
  const float* bv = (const float*)d_in[6];
  const float* wo = (const float*)d_in[7];
  const float* bo = (const float*)d_in[8];
  float* out = (float*)d_out;

  unsigned short* p = (unsigned short*)d_ws;
  unsigned short* Xbf = p;                        p += (size_t)ROWS * EMB;
  unsigned short* Wqb = p;                        p += (size_t)EMB * EMB;
  unsigned short* Wkb = p;                        p += (size_t)EMB * EMB;
  unsigned short* Wvb = p;                        p += (size_t)EMB * EMB;
  unsigned short* Wob = p;                        p += (size_t)EMB * EMB;
  unsigned short* Qb  = p;                        p += (size_t)ROWS * EMB;   // [B,H,S,DH]
  unsigned short* Kb  = p;                        p += (size_t)ROWS * EMB;   // [B,H,S,DH]
  unsigned short* Vtg = p;                        p += (size_t)ROWS * EMB;   // [B,H,DH,S] kv-permuted
  unsigned short* Ctx = p;                        p += (size_t)ROWS * EMB;

  cvt_all_kernel<<<4096, 256, 0, stream>>>(query, wq, wk, wv, wo,
                                           Xbf, Wqb, Wkb, Wvb, Wob);
  gemm_qkv_kernel<<<dim3(ROWS / 128, EMB / 128, 3), 256, 0, stream>>>(
      Xbf, Wqb, Wkb, Wvb, bq, bk, bv, Qb, Kb, Vtg);
  attn_kernel<<<dim3(BATCH * NH, S_LEN / 128), 512, 0, stream>>>(Qb, Kb, Vtg, Ctx);
  gemm_out_kernel<<<dim3(ROWS / 64, EMB / 128), 256, 0, stream>>>(Ctx, Wob, bo, out);
}

// Round 10
// 194.594 us; speedup vs baseline: 1.3634x; 1.0018x over previous
//
#include <hip/hip_runtime.h>
#include <hip/hip_bf16.h>
#include <stdint.h>

// Problem constants
#define S_LEN 2048
#define BATCH 2
#define EMB   1024
#define NH    16
#define DHEAD 64
#define ROWS  (S_LEN*BATCH)   // 4096
// DH^-0.5 * log2(e): scores produced in log2 domain so softmax uses raw v_exp_f32
#define SCALE_Q 0.18033688011112042f
#define DEFER_THR 11.0f       // log2-domain defer-max threshold (P <= 2^11)

typedef __attribute__((ext_vector_type(8))) short bf16x8;    // 8 bf16 in 4 VGPRs
typedef __attribute__((ext_vector_type(4))) float f32x4;
typedef __attribute__((ext_vector_type(16))) float f32x16;

typedef const __attribute__((address_space(1))) void* gas_ptr;
typedef __attribute__((address_space(3))) void* las_ptr;
// async global->LDS, 16B per lane, dest = wave-uniform base + lane*16
#define GLD16(g, l) __builtin_amdgcn_global_load_lds((gas_ptr)(g), (las_ptr)(l), 16, 0, 0)

__device__ __forceinline__ unsigned short f2b(float f) {
  union { float f; unsigned int u; } v; v.f = f;
  unsigned int u = v.u;
  unsigned int r = (u + 0x7FFFu + ((u >> 16) & 1u)) >> 16;  // RNE
  return (unsigned short)r;
}

__device__ __forceinline__ unsigned cvt_pk_bf16(float lo, float hi) {
  unsigned r;
  asm("v_cvt_pk_bf16_f32 %0, %1, %2" : "=v"(r) : "v"(lo), "v"(hi));
  return r;
}

// raw 2^x — single transcendental instruction, no ocml edge-case bloat
__device__ __forceinline__ float exp2_raw(float x) {
  float r;
  asm("v_exp_f32 %0, %1" : "=v"(r) : "v"(x));
  return r;
}

// ---------------- fused fp32 -> bf16 conversion (query + 4 weights) ----------------
__device__ __forceinline__ void cvt8(const float* __restrict__ s,
                                     unsigned short* __restrict__ d, size_t i) {
  float4 a = *reinterpret_cast<const float4*>(s + i);
  float4 b = *reinterpret_cast<const float4*>(s + i + 4);
  uint4 o;
  o.x = (unsigned)f2b(a.x) | ((unsigned)f2b(a.y) << 16);
  o.y = (unsigned)f2b(a.z) | ((unsigned)f2b(a.w) << 16);
  o.z = (unsigned)f2b(b.x) | ((unsigned)f2b(b.y) << 16);
  o.w = (unsigned)f2b(b.z) | ((unsigned)f2b(b.w) << 16);
  *reinterpret_cast<uint4*>(d + i) = o;
}

__global__ __launch_bounds__(256) void cvt_all_kernel(
    const float* __restrict__ query,
    const float* __restrict__ wq, const float* __restrict__ wk,
    const float* __restrict__ wv, const float* __restrict__ wo,
    unsigned short* __restrict__ Xbf,
    unsigned short* __restrict__ Wqb, unsigned short* __restrict__ Wkb,
    unsigned short* __restrict__ Wvb, unsigned short* __restrict__ Wob) {
  int id = blockIdx.x;
  const float* s; unsigned short* d; size_t off;
  if (id < 2048) { s = query; d = Xbf; off = (size_t)id * 2048; }
  else {
    int wsel = (id - 2048) >> 9;
    off = (size_t)((id - 2048) & 511) * 2048;
    switch (wsel) {
      case 0:  s = wq; d = Wqb; break;
      case 1:  s = wk; d = Wkb; break;
      case 2:  s = wv; d = Wvb; break;
      default: s = wo; d = Wob; break;
    }
  }
  cvt8(s, d, off + (size_t)threadIdx.x * 8);
}

// ---------------- GEMM mainloop: 128x128 tile, BK=32, TRIPLE-buffered ----------------
// Counted-vmcnt 2-deep pipeline (T3/T4-minimum): stage tile t+2 after compute(t),
// steady-state vmcnt(VW) (never 0 mid-loop), ONE barrier/iter with
// lgkmcnt(0)+sched_barrier(0) before it. LDS 48 KB (A 24 + B 24).
// NWAVE=4: per-wave 64x64 out (NJ=4). NWAVE=8: per-wave 64x32 (NJ=2).
template <int NWAVE, int NJ>
__device__ __forceinline__ void gemm_pipe(const unsigned short* __restrict__ A,
                                          const unsigned short* __restrict__ Bw,
                                          int m0, int n0, f32x4 (&acc)[4][NJ],
                                          unsigned short* __restrict__ SH) {
  const int T   = NWAVE * 64;
  const int GQ  = 512 / T;            // GLD16 per thread per matrix per tile
  const int t    = threadIdx.x;
  const int lane = t & 63;
  const int w    = t >> 6;
  const int wcw  = NWAVE / 2;         // waves along n
  const int wr   = w / wcw, wc = w % wcw;
  const int nspan = 128 / wcw;        // 64 or 32
  const int lm = lane & 15, lq = lane >> 4;
  unsigned short* Ab = SH;            // [3][128*32]
  unsigned short* Bb = SH + 3 * 4096; // [3][128*32]

  f32x4 zf = {0.0f, 0.0f, 0.0f, 0.0f};
#pragma unroll
  for (int i = 0; i < 4; ++i)
#pragma unroll
    for (int j = 0; j < NJ; ++j) acc[i][j] = zf;

  // stage one 128x32 A-tile + B-tile into buffer buf: 512 chunks of 16B each;
  // chunk c -> row c>>2, phys slot c&3 holds logical chunk (c&3)^(row&3).
  auto STAGE = [&](int buf, int k0) {
#pragma unroll
    for (int q = 0; q < GQ; ++q) {
      int c = t + q * T;
      int r = c >> 2, ci = c & 3;
      int lc = ci ^ (r & 3);
      GLD16(A  + (size_t)(m0 + r) * EMB + k0 + lc * 8,
            (char*)Ab + buf * 8192 + (size_t)(q * T + w * 64) * 16);
      GLD16(Bw + (size_t)(n0 + r) * EMB + k0 + lc * 8,
            (char*)Bb + buf * 8192 + (size_t)(q * T + w * 64) * 16);
    }
  };

  const int NT = EMB / 32;            // 32 K-tiles
  STAGE(0, 0);
  STAGE(1, 32);
  if (GQ == 2) { asm volatile("s_waitcnt vmcnt(4)" ::: "memory"); }
  else         { asm volatile("s_waitcnt vmcnt(2)" ::: "memory"); }
  __builtin_amdgcn_s_barrier();

  for (int it = 0; it < NT; ++it) {
    const int cur = it % 3;
    const unsigned short* Ac = Ab + cur * 4096;
    const unsigned short* Bc = Bb + cur * 4096;
    bf16x8 af[4], bfr[NJ];
#pragma unroll
    for (int i = 0; i < 4; ++i) {
      int ra = wr * 64 + i * 16 + lm;
      af[i] = *reinterpret_cast<const bf16x8*>(&Ac[ra * 32 + (lq ^ (ra & 3)) * 8]);
    }
#pragma unroll
    for (int j = 0; j < NJ; ++j) {
      int rb = wc * nspan + j * 16 + lm;
      bfr[j] = *reinterpret_cast<const bf16x8*>(&Bc[rb * 32 + (lq ^ (rb & 3)) * 8]);
    }
    __builtin_amdgcn_s_setprio(1);
#pragma unroll
    for (int i = 0; i < 4; ++i)
#pragma unroll
      for (int j = 0; j < NJ; ++j)
        acc[i][j] = __builtin_amdgcn_mfma_f32_16x16x32_bf16(af[i], bfr[j], acc[i][j], 0, 0, 0);
    __builtin_amdgcn_s_setprio(0);

    if (it + 2 < NT) {
      STAGE((it + 2) % 3, (it + 2) * 32);
      // my reads of buf[cur] retired + my stage for tile it+1 landed
      if (GQ == 2) asm volatile("s_waitcnt vmcnt(4) lgkmcnt(0)" ::: "memory");
      else         asm volatile("s_waitcnt vmcnt(2) lgkmcnt(0)" ::: "memory");
    } else {
      asm volatile("s_waitcnt vmcnt(0) lgkmcnt(0)" ::: "memory");
    }
    __builtin_amdgcn_sched_barrier(0);
    __builtin_amdgcn_s_barrier();
  }
}

// ---------------- QKV projection (V written pre-transposed + kv-permuted) ----------------
__global__ __launch_bounds__(256) void gemm_qkv_kernel(
    const unsigned short* __restrict__ X,
    const unsigned short* __restrict__ Wq, const unsigned short* __restrict__ Wk,
    const unsigned short* __restrict__ Wv,
    const float* __restrict__ bq, const float* __restrict__ bk, const float* __restrict__ bv,
    unsigned short* __restrict__ Qb, unsigned short* __restrict__ Kb,
    unsigned short* __restrict__ Vtg) {
  __shared__ unsigned short SH[24576];   // 48 KB: triple-buffered A|B
  const int m0 = blockIdx.x * 128;
  const int n0 = blockIdx.y * 128;
  const int z  = blockIdx.z;
  const unsigned short* Bw = (z == 0) ? Wq : (z == 1) ? Wk : Wv;
  const float* bias        = (z == 0) ? bq : (z == 1) ? bk : bv;

  f32x4 acc[4][4];
  gemm_pipe<4, 4>(X, Bw, m0, n0, acc, SH);

  const int t    = threadIdx.x;
  const int lane = t & 63;
  const int w    = t >> 6;
  const int wr   = w >> 1, wc = w & 1;
  const int lm   = lane & 15, lq = lane >> 4;

  if (z != 2) {
    unsigned short* Out = (z == 0) ? Qb : Kb;
    const float scale   = (z == 0) ? SCALE_Q : 1.0f;
#pragma unroll
    for (int j = 0; j < 4; ++j) {
      int col = n0 + wc * 64 + j * 16 + lm;      // E index
      int h = col >> 6, dd = col & 63;
      float bc = bias[col];
#pragma unroll
      for (int i = 0; i < 4; ++i) {
#pragma unroll
        for (int r = 0; r < 4; ++r) {
          int row = m0 + wr * 64 + i * 16 + lq * 4 + r;   // s*B + b
          int s = row >> 1, b = row & 1;
          float v = (acc[i][j][r] + bc) * scale;
          Out[((size_t)(b * NH + h) * S_LEN + s) * DHEAD + dd] = f2b(v);
        }
      }
    }
  } else {
    // V: transpose in LDS, write Vt[bh][d][s'] with kv bits2<->3 swapped per
    // 16-group (matches attn's in-register P ordering for the PV MFMA).
    unsigned short* T = SH;   // 128*128 shorts = 32 KB (of 48 KB)
    __syncthreads();          // mainloop fully done before repurposing SH
#pragma unroll
    for (int j = 0; j < 4; ++j) {
      int col = wc * 64 + j * 16 + lm;           // local col 0..127
      float bc = bias[n0 + col];
#pragma unroll
      for (int i = 0; i < 4; ++i) {
#pragma unroll
        for (int r = 0; r < 4; ++r) {
          int row = wr * 64 + i * 16 + lq * 4 + r;   // local row 0..127
          int idx = (row & 1) * 64 + (row >> 1);
          int chunk = idx >> 3, within = idx & 7;
          int pchunk = (chunk & 8) | ((chunk ^ col) & 7);
          T[col * 128 + pchunk * 8 + within] = f2b(acc[i][j][r] + bc);
        }
      }
    }
    __syncthreads();
#pragma unroll
    for (int itr = 0; itr < 8; ++itr) {
      int u = (t >> 3) + itr * 32;
      int col = u & 127, b = u >> 7;
      int c3 = t & 7;
      int pchunk = (b * 8) | ((c3 ^ col) & 7);
      bf16x8 vv = *reinterpret_cast<const bf16x8*>(&T[col * 128 + pchunk * 8]);
      int h = (n0 + col) >> 6, dd = (n0 + col) & 63;
      unsigned short* dst =
          Vtg + ((size_t)(b * NH + h) * DHEAD + dd) * S_LEN + (m0 >> 1);
      // kv-permute store: 8-run c3*8 -> two 4-runs (swap bits 2,3)
      int p1 = ((c3 >> 1) << 4) | ((c3 & 1) << 2);
      union { bf16x8 v; uint4 u4; } cv; cv.v = vv;
      *reinterpret_cast<uint2*>(dst + p1)     = make_uint2(cv.u4.x, cv.u4.y);
      *reinterpret_cast<uint2*>(dst + p1 + 8) = make_uint2(cv.u4.z, cv.u4.w);
    }
  }
}

// ---------------- final projection: 128x128 tile, 8 waves, pipelined ----------------
__global__ __launch_bounds__(512) void gemm_out_kernel(
    const unsigned short* __restrict__ Ctx, const unsigned short* __restrict__ Wo,
    const float* __restrict__ bo, float* __restrict__ Out) {
  __shared__ unsigned short SH[24576];   // 48 KB
  const int m0 = blockIdx.x * 128;
  const int n0 = blockIdx.y * 128;

  f32x4 acc[4][2];
  gemm_pipe<8, 2>(Ctx, Wo, m0, n0, acc, SH);

  const int t    = threadIdx.x;
  const int lane = t & 63;
  const int w    = t >> 6;
  const int wr   = w >> 2, wc = w & 3;
  const int lm   = lane & 15, lq = lane >> 4;
#pragma unroll
  for (int j = 0; j < 2; ++j) {
    int col = n0 + wc * 32 + j * 16 + lm;
    float bc = bo[col];
#pragma unroll
    for (int i = 0; i < 4; ++i) {
#pragma unroll
      for (int r = 0; r < 4; ++r) {
        int row = m0 + wr * 64 + i * 16 + lq * 4 + r;
        Out[(size_t)row * EMB + col] = acc[i][j][r] + bc;
      }
    }
  }
}

// ---------------- flash attention (frozen from R9) ----------------
__global__ __launch_bounds__(512, 4) void attn_kernel(
    const unsigned short* __restrict__ Qb, const unsigned short* __restrict__ Kb,
    const unsigned short* __restrict__ Vtg, unsigned short* __restrict__ Ctx) {
  const int bh = blockIdx.x;
  const int q0 = blockIdx.y * 128;
  const int t    = threadIdx.x;
  const int lane = t & 63;
  const int w    = t >> 6;        // 0..7
  const int hf   = w >> 2;        // kv half
  const int wl   = w & 3;         // wave within half
  const int th   = t & 255;       // thread within half
  const int l31  = lane & 31;
  const int hh   = lane >> 5;
  const unsigned short* Q  = Qb  + (size_t)bh * S_LEN * DHEAD;
  const unsigned short* K  = Kb  + (size_t)bh * S_LEN * DHEAD;
  const unsigned short* Vt = Vtg + (size_t)bh * DHEAD * S_LEN;   // [d][s-permuted]

  alignas(16) __shared__ char SMEM[65536];
  unsigned short* Kl = (unsigned short*)(SMEM + hf * 32768);           // [2][4096]
  unsigned short* Vl = (unsigned short*)(SMEM + hf * 32768 + 16384);   // [2][4096]

  const int qw = q0 + wl * 32;

  bf16x8 aq[4];
#pragma unroll
  for (int kk = 0; kk < 4; ++kk)
    aq[kk] = *reinterpret_cast<const bf16x8*>(
        Q + (size_t)(qw + l31) * DHEAD + kk * 16 + hh * 8);

  f32x16 z16 = {0.f,0.f,0.f,0.f, 0.f,0.f,0.f,0.f, 0.f,0.f,0.f,0.f, 0.f,0.f,0.f,0.f};
  f32x16 accO[2];
  accO[0] = z16; accO[1] = z16;
  float m_s = -1e30f, l_s = 0.0f;

  auto STAGE = [&](int b, int kb) {
#pragma unroll
    for (int q = 0; q < 2; ++q) {
      int c = th + q * 256;
      int r = c >> 3, pp = c & 7;
      int lc = pp ^ (r & 7);
      GLD16(K + (size_t)(kb + r) * DHEAD + lc * 8,
            (char*)Kl + (size_t)b * 8192 + (size_t)(q * 256 + wl * 64) * 16);
      GLD16(Vt + (size_t)r * S_LEN + kb + lc * 8,
            (char*)Vl + (size_t)b * 8192 + (size_t)(q * 256 + wl * 64) * 16);
    }
  };

  const int kvbase = hf * (S_LEN / 2);
  const int NT = S_LEN / 2 / 64;    // 16 tiles per half
  STAGE(0, kvbase);
  STAGE(1, kvbase + 64);

  for (int it = 0; it < NT; ++it) {
    const int cur = it & 1;
    if (it < NT - 1) {
      asm volatile("s_waitcnt vmcnt(4)" ::: "memory");
    } else {
      asm volatile("s_waitcnt vmcnt(0)" ::: "memory");
    }
    __builtin_amdgcn_s_barrier();

    const unsigned short* Klc = Kl + cur * 4096;
    const unsigned short* Vlc = Vl + cur * 4096;

    f32x16 p32[2];
    __builtin_amdgcn_s_setprio(1);
#pragma unroll
    for (int ji = 0; ji < 2; ++ji) {
      f32x16 a = z16;
      int rr = ji * 32 + l31;
#pragma unroll
      for (int kk = 0; kk < 4; ++kk) {
        bf16x8 kf = *reinterpret_cast<const bf16x8*>(
            &Klc[rr * 64 + ((kk * 2 + hh) ^ (rr & 7)) * 8]);
        a = __builtin_amdgcn_mfma_f32_32x32x16_bf16(kf, aq[kk], a, 0, 0, 0);
      }
      p32[ji] = a;
    }
    __builtin_amdgcn_s_setprio(0);

    float t8[8];
#pragma unroll
    for (int e = 0; e < 8; ++e)
      t8[e] = fmaxf(fmaxf(p32[0][e], p32[0][e + 8]),
                    fmaxf(p32[1][e], p32[1][e + 8]));
    float u0 = fmaxf(t8[0], t8[4]), u1 = fmaxf(t8[1], t8[5]);
    float u2 = fmaxf(t8[2], t8[6]), u3 = fmaxf(t8[3], t8[7]);
    float tm = fmaxf(fmaxf(u0, u1), fmaxf(u2, u3));
    tm = fmaxf(tm, __shfl_xor(tm, 32));

    if (!__all(tm - m_s <= DEFER_THR)) {
      float mn = fmaxf(m_s, tm);
      float sc = exp2_raw(m_s - mn);
      l_s *= sc;
      m_s = mn;
#pragma unroll
      for (int r = 0; r < 16; ++r) {
        float scr = __shfl(sc, (r & 3) + 8 * (r >> 2) + 4 * hh);
        accO[0][r] *= scr;
        accO[1][r] *= scr;
      }
    }

#pragma unroll
    for (int e = 0; e < 16; ++e) {
      p32[0][e] = exp2_raw(p32[0][e] - m_s);
      p32[1][e] = exp2_raw(p32[1][e] - m_s);
    }
    float s8[8];
#pragma unroll
    for (int e = 0; e < 8; ++e)
      s8[e] = (p32[0][e] + p32[0][e + 8]) + (p32[1][e] + p32[1][e + 8]);
    float v0 = (s8[0] + s8[4]) + (s8[1] + s8[5]);
    float v1 = (s8[2] + s8[6]) + (s8[3] + s8[7]);
    float ps = v0 + v1;
    ps += __shfl_xor(ps, 32);
    l_s += ps;

    bf16x8 pa[2][2];
#pragma unroll
    for (int ji = 0; ji < 2; ++ji) {
      uint4 lo4, hi4;
      lo4.x = cvt_pk_bf16(p32[ji][0],  p32[ji][1]);
      lo4.y = cvt_pk_bf16(p32[ji][2],  p32[ji][3]);
      lo4.z = cvt_pk_bf16(p32[ji][4],  p32[ji][5]);
      lo4.w = cvt_pk_bf16(p32[ji][6],  p32[ji][7]);
      hi4.x = cvt_pk_bf16(p32[ji][8],  p32[ji][9]);
      hi4.y = cvt_pk_bf16(p32[ji][10], p32[ji][11]);
      hi4.z = cvt_pk_bf16(p32[ji][12], p32[ji][13]);
      hi4.w = cvt_pk_bf16(p32[ji][14], p32[ji][15]);
      pa[ji][0] = *reinterpret_cast<bf16x8*>(&lo4);
      pa[ji][1] = *reinterpret_cast<bf16x8*>(&hi4);
    }

    __builtin_amdgcn_s_setprio(1);
#pragma unroll
    for (int ni = 0; ni < 2; ++ni) {
      int dd = ni * 32 + l31;
#pragma unroll
      for (int ji = 0; ji < 2; ++ji)
#pragma unroll
        for (int ss = 0; ss < 2; ++ss) {
          bf16x8 bv = *reinterpret_cast<const bf16x8*>(
              &Vlc[dd * 64 + ((ji * 4 + ss * 2 + hh) ^ (dd & 7)) * 8]);
          accO[ni] = __builtin_amdgcn_mfma_f32_32x32x16_bf16(pa[ji][ss], bv, accO[ni], 0, 0, 0);
        }
    }
    __builtin_amdgcn_s_setprio(0);

    asm volatile("s_waitcnt lgkmcnt(0)" ::: "memory");
    __builtin_amdgcn_sched_barrier(0);
    __builtin_amdgcn_s_barrier();

    if (it + 2 < NT) STAGE(cur, kvbase + (it + 2) * 64);
  }

  // ---- flash-decode merge of the two kv-halves (LDS reused after final barrier)
  float* MB = (float*)SMEM;
  const int MS = 35;
  const int mb = (wl * 64 + lane) * MS;
  if (hf == 1) {
    MB[mb]     = m_s;
    MB[mb + 1] = l_s;
#pragma unroll
    for (int r = 0; r < 16; ++r) {
      MB[mb + 2 + r]  = accO[0][r];
      MB[mb + 18 + r] = accO[1][r];
    }
  }
  __syncthreads();
  if (hf == 0) {
    float m1 = MB[mb], l1 = MB[mb + 1];
    float mn  = fmaxf(m_s, m1);
    float sc0 = exp2_raw(m_s - mn);
    float sc1 = exp2_raw(m1 - mn);
    float lf  = l_s * sc0 + l1 * sc1;
    const int b = bh >> 4, h = bh & 15;
#pragma unroll
    for (int r = 0; r < 16; ++r) {
      int row = (r & 3) + 8 * (r >> 2) + 4 * hh;
      float s0 = __shfl(sc0, row);
      float s1 = __shfl(sc1, row);
      float rl = 1.0f / __shfl(lf, row);
      float o0 = (accO[0][r] * s0 + MB[mb + 2 + r]  * s1) * rl;
      float o1 = (accO[1][r] * s0 + MB[mb + 18 + r] * s1) * rl;
      int srow = qw + row;
      size_t base = ((size_t)srow * BATCH + b) * EMB + (size_t)h * 64 + l31;
      Ctx[base]      = f2b(o0);
      Ctx[base + 32] = f2b(o1);
    }
  }
}

// ---------------- launch ----------------
extern "C" void kernel_launch(void* const* d_in, const int* in_sizes, int n_in,
                              void* d_out, int out_size, void* d_ws, size_t ws_size,
                              hipStream_t stream) {
  const float* query = (const float*)d_in[0];
  const float* wq = (const float*)d_in[1];
  const float* bq = (const float*)d_in[2];
  const float* wk = (const float*)d_in[3];
  const float* bk = (const float*)d_in[4];
  const float* wv = (const float*)d_in[5];
  const float* bv = (const float*)d_in[6];
  const float* wo = (const float*)d_in[7];
  const float* bo = (const float*)d_in[8];
  float* out = (float*)d_out;

  unsigned short* p = (unsigned short*)d_ws;
  unsigned short* Xbf = p;                        p += (size_t)ROWS * EMB;
  unsigned short* Wqb = p;                        p += (size_t)EMB * EMB;
  unsigned short* Wkb = p;                        p += (size_t)EMB * EMB;
  unsigned short* Wvb = p;                        p += (size_t)EMB * EMB;
  unsigned short* Wob = p;                        p += (size_t)EMB * EMB;
  unsigned short* Qb  = p;                        p += (size_t)ROWS * EMB;   // [B,H,S,DH]
  unsigned short* Kb  = p;                        p += (size_t)ROWS * EMB;   // [B,H,S,DH]
  unsigned short* Vtg = p;                        p += (size_t)ROWS * EMB;   // [B,H,DH,S] kv-permuted
  unsigned short* Ctx = p;                        p += (size_t)ROWS * EMB;

  cvt_all_kernel<<<4096, 256, 0, stream>>>(query, wq, wk, wv, wo,
                                           Xbf, Wqb, Wkb, Wvb, Wob);
  gemm_qkv_kernel<<<dim3(ROWS / 128, EMB / 128, 3), 256, 0, stream>>>(
      Xbf, Wqb, Wkb, Wvb, bq, bk, bv, Qb, Kb, Vtg);
  attn_kernel<<<dim3(BATCH * NH, S_LEN / 128), 512, 0, stream>>>(Qb, Kb, Vtg, Ctx);
  gemm_out_kernel<<<dim3(ROWS / 128, EMB / 128), 512, 0, stream>>>(Ctx, Wob, bo, out);
}